// Round 2
// baseline (415.453 us; speedup 1.0000x reference)
//
#include <hip/hip_runtime.h>
#include <stdint.h>

typedef short v8s __attribute__((ext_vector_type(8)));
typedef short v4s __attribute__((ext_vector_type(4)));
typedef float v4f __attribute__((ext_vector_type(4)));

#define BM 256         // rows per block (8 waves, wave grid 4x2)
#define BN 128
#define BK 64          // shorts per row per k-chunk (128 B)
#define BSH (BN * BK)  // B tile: 8192 shorts = 16 KB
#define POS_INF __builtin_inff()

typedef __attribute__((address_space(3))) unsigned int lds_uint;
typedef const __attribute__((address_space(1))) unsigned int glb_uint;

__device__ __forceinline__ void load16_lds(const void* g, void* l) {
    // 16B per lane, LDS dest = wave-uniform base + lane*16
    __builtin_amdgcn_global_load_lds((glb_uint*)g, (lds_uint*)l, 16, 0, 0);
}

__device__ __forceinline__ short f2bf(float f) {
    uint32_t u = __builtin_bit_cast(uint32_t, f);
    u += 0x7fffu + ((u >> 16) & 1u);
    return (short)(u >> 16);
}

// Fused prep (unchanged): blocks [0, CB) normalize centers (1 row per wave)
// and pad rows [C, CP) with zeros, plus zero the rowblock counters and
// d_out; blocks [CB, ...) convert x fp32->bf16 at pure memory BW.
__global__ void prep(const float* __restrict__ centers,
                     unsigned short* __restrict__ cbf,
                     int C, int D, int CP, int CB,
                     const float* __restrict__ x,
                     unsigned short* __restrict__ xbf, size_t nx,
                     int* __restrict__ cnt, int NB,
                     float* __restrict__ out) {
    const int b = blockIdx.x;
    const int t = threadIdx.x;
    if (b == 0 && t == 0) out[0] = 0.0f;
    if (b < CB) {
        const int g = b * 256 + t;
        if (g < NB) cnt[g] = 0;
        const int wave = t >> 6, lane = t & 63;
        const int row = b * 4 + wave;
        if (row >= CP) return;
        if (row >= C) {
            v4s z = {0, 0, 0, 0};
            for (int d = lane * 4; d < D; d += 256)
                *(v4s*)&cbf[(size_t)row * D + d] = z;
            return;
        }
        const float* src = centers + (size_t)row * D;
        float ss = 0.0f;
        for (int d = lane * 4; d < D; d += 256) {
            v4f f = *(const v4f*)&src[d];
            ss += f.x * f.x + f.y * f.y + f.z * f.z + f.w * f.w;
        }
        #pragma unroll
        for (int off = 32; off; off >>= 1) ss += __shfl_xor(ss, off, 64);
        const float rn = rsqrtf(ss);
        for (int d = lane * 4; d < D; d += 256) {
            v4f f = *(const v4f*)&src[d];
            v4s s;
            s.x = f2bf(f.x * rn); s.y = f2bf(f.y * rn);
            s.z = f2bf(f.z * rn); s.w = f2bf(f.w * rn);
            *(v4s*)&cbf[(size_t)row * D + d] = s;
        }
    } else {
        const size_t i = ((size_t)(b - CB) * 256 + t) * 8;
        if (i >= nx) return;
        v4f f0 = *(const v4f*)&x[i];
        v4f f1 = *(const v4f*)&x[i + 4];
        v8s s;
        s[0] = f2bf(f0.x); s[1] = f2bf(f0.y); s[2] = f2bf(f0.z); s[3] = f2bf(f0.w);
        s[4] = f2bf(f1.x); s[5] = f2bf(f1.y); s[6] = f2bf(f1.z); s[7] = f2bf(f1.w);
        *(v8s*)&xbf[i] = s;
    }
}

// Fused GEMM + row-min epilogue + last-block finisher.
// 256x128 tile, 512 threads = 8 waves (4x2, 64x64/wave), 16x16x32 MFMA.
//
// R2 structural change vs the 283us kernel: A is NOT staged through LDS.
// Wave grid 4x2 means each A 64-row panel is read by only 2 waves and each
// A fragment element is consumed once (j-reuse lives in registers), so the
// A DMA+LDS round-trip (2/3 of staging volume, 2/3 of the per-tile
// syncthreads drain) bought zero reuse. A fragments now load straight from
// global (L2/L3-resident; 4 q-lanes fall in one 64B line -> full line use;
// the wn-pair gives L1 hits). B (4-way wave-shared) stays in LDS, now
// DOUBLE-buffered 2x16KB: B-DMA for tile t+1 is issued AFTER tile t's
// A-loads, so the compiler's auto vmcnt(2) waits for A keep the prefetch
// in flight under the MFMAs; the end-of-tile __syncthreads (vmcnt 0 drain)
// retires it ~a whole tile after issue. One barrier per K-tile (was 2).
// MFMA accumulate order (kh=0 then 1 per acc element) identical to the
// verified kernel -> bit-identical numerics.
//
// Cross-block protocol unchanged: NO acquire/release fences (agent-scope
// ACQ_REL RMW emits buffer_inv/buffer_wbl2 = per-XCD L2 flush; measured
// +59% k-loop time). pos/partial use RELAXED agent-scope atomics;
// __syncthreads drains vmcnt(0) before the RELAXED counter RMW; RMW total
// order + control dependency orders the finisher's relaxed loads.
__global__ void __launch_bounds__(512)
gemm_fused(const unsigned short* __restrict__ xbf,
           const unsigned short* __restrict__ cbf,
           const int* __restrict__ labels,
           float* __restrict__ pos, float* __restrict__ partial,
           int* __restrict__ cnt,
           int Bt, int C, int D, int NT, float margin,
           float* __restrict__ out) {
    __shared__ short Bsbuf[2 * BSH];   // 32 KB total (double-buffered B)

    const int t   = threadIdx.x;
    const int bid = blockIdx.x;
    const int xcd = bid & 7;
    const int per = bid >> 3;
    const int rowblk = (per >> 3) * 8 + xcd;
    const int nt     = per & 7;
    const int row0 = rowblk * BM;
    const int n0   = nt * BN;

    const int lane = t & 63;
    const int wave = t >> 6;          // 0..7
    const int wm = wave >> 1;         // 0..3 -> m offset wm*64
    const int wn = wave & 1;          // 0..1 -> n offset wn*64
    const int l15 = lane & 15, q = lane >> 4;

    // B staging lane decomposition: 8 rows x 8 chunks per DMA instruction.
    // LDS invariant (proven 0-conflict): row r, slot chunk s holds source
    // chunk s^(r&7); DMA writes base+lane*16 so the SOURCE is permuted.
    const int rsub = lane >> 3;              // row within 8-row group
    const int csrc = (lane & 7) ^ rsub;      // swizzled source chunk

    // prefetch this thread's label before the k-loop (latency hidden)
    int myLab = 0;
    if (t < BM) myLab = labels[row0 + t];

    // per-lane A base: row = row0 + wm*64 + l15 (+i*16), k-chunk = q*8
    const unsigned short* gAl = xbf + (size_t)(row0 + wm * 64 + l15) * D + q * 8;

    v4f acc[4][4];
    #pragma unroll
    for (int i = 0; i < 4; ++i)
        #pragma unroll
        for (int j = 0; j < 4; ++j)
            acc[i][j] = (v4f){0.f, 0.f, 0.f, 0.f};

    const int KT = D / BK;   // 8

    // prologue: stage B tile 0 into buf0; syncthreads drains the DMA.
    #pragma unroll
    for (int p = 0; p < 2; ++p) {
        const int rbase = wave * 16 + p * 8;
        load16_lds(&cbf[(size_t)(n0 + rbase + rsub) * D + csrc * 8],
                   &Bsbuf[rbase * BK]);
    }
    __syncthreads();

    for (int kt = 0; kt < KT; ++kt) {
        const int k0 = kt * BK;
        const short* Bc = Bsbuf + (kt & 1) * BSH;
        short*       Bn = Bsbuf + ((kt & 1) ^ 1) * BSH;

        // B fragments from LDS (lgkmcnt-tracked)
        v8s b[4][2];
        #pragma unroll
        for (int j = 0; j < 4; ++j) {
            const int n = wn * 64 + j * 16 + l15;
            #pragma unroll
            for (int kh = 0; kh < 2; ++kh)
                b[j][kh] = *(const v8s*)&Bc[n * BK + ((((kh << 2) + q) ^ (l15 & 7)) << 3)];
        }
        // A fragments straight from global (vmcnt-tracked)
        v8s a[4][2];
        #pragma unroll
        for (int i = 0; i < 4; ++i)
            #pragma unroll
            for (int kh = 0; kh < 2; ++kh)
                a[i][kh] = *(const v8s*)&gAl[(size_t)i * 16 * D + k0 + kh * 32];
        // prefetch next B tile AFTER the A-loads: A's auto-waits are then
        // vmcnt(2), keeping these 2 DMA in flight under the MFMAs below.
        if (kt + 1 < KT) {
            #pragma unroll
            for (int p = 0; p < 2; ++p) {
                const int rbase = wave * 16 + p * 8;
                load16_lds(&cbf[(size_t)(n0 + rbase + rsub) * D + (k0 + BK) + csrc * 8],
                           &Bn[rbase * BK]);
            }
        }
        #pragma unroll
        for (int kh = 0; kh < 2; ++kh)
            #pragma unroll
            for (int i = 0; i < 4; ++i)
                #pragma unroll
                for (int j = 0; j < 4; ++j)
                    acc[i][j] = __builtin_amdgcn_mfma_f32_16x16x32_bf16(
                        a[i][kh], b[j][kh], acc[i][j], 0, 0, 0);
        __syncthreads();   // drains vmcnt(0): next B tile landed; barrier
    }

    // ---- Epilogue (Bsbuf dead; alias scratch) ----
    int*   Ls    = (int*)Bsbuf;                     // [BM] labels (1 KB)
    float* sMinW = (float*)((char*)Bsbuf + 1024);   // [2*BM] (2 KB)
    int*   sLast = (int*)((char*)Bsbuf + 3072);
    float* wsum  = (float*)((char*)Bsbuf + 3088);   // 8 floats
    if (t < BM) Ls[t] = myLab;
    __syncthreads();

    // dist = 1 - acc; stash pos at label col; row-min over valid cols.
    // C/D layout (16x16x32): col = lane&15, row = q*4 + reg
    #pragma unroll
    for (int i = 0; i < 4; ++i) {
        #pragma unroll
        for (int rg = 0; rg < 4; ++rg) {
            const int row_l = wm * 64 + i * 16 + q * 4 + rg;
            const int lab = Ls[row_l];
            float m = POS_INF;
            #pragma unroll
            for (int j = 0; j < 4; ++j) {
                const int col = n0 + wn * 64 + j * 16 + l15;
                const float d = 1.0f - acc[i][j][rg];
                if (col == lab)
                    __hip_atomic_store(&pos[row0 + row_l], d,
                                       __ATOMIC_RELAXED, __HIP_MEMORY_SCOPE_AGENT);
                else if (col < C) m = fminf(m, d);
            }
            m = fminf(m, __shfl_xor(m, 1, 64));
            m = fminf(m, __shfl_xor(m, 2, 64));
            m = fminf(m, __shfl_xor(m, 4, 64));
            m = fminf(m, __shfl_xor(m, 8, 64));
            if (l15 == 0) sMinW[wn * BM + row_l] = m;
        }
    }
    __syncthreads();
    if (t < BM) {
        const float m = fminf(sMinW[t], sMinW[BM + t]);
        __hip_atomic_store(&partial[(size_t)nt * Bt + row0 + t], m,
                           __ATOMIC_RELAXED, __HIP_MEMORY_SCOPE_AGENT);
    }
    __syncthreads();  // drains vmcnt(0): all stores at coherence point

    // Completion counter: RELAXED on purpose (no buffer_inv/buffer_wbl2).
    if (t == 0) {
        __builtin_amdgcn_s_waitcnt(0);  // belt-and-braces; already drained
        const int old = __hip_atomic_fetch_add(&cnt[rowblk], 1,
                                               __ATOMIC_RELAXED,
                                               __HIP_MEMORY_SCOPE_AGENT);
        *sLast = (old == NT - 1);
    }
    __syncthreads();
    if (!*sLast) return;

    float hng = 0.0f;
    if (t < BM) {
        const int r = row0 + t;
        float neg = POS_INF;
        for (int tt = 0; tt < NT; ++tt)
            neg = fminf(neg, __hip_atomic_load(&partial[(size_t)tt * Bt + r],
                                               __ATOMIC_RELAXED,
                                               __HIP_MEMORY_SCOPE_AGENT));
        const float p = __hip_atomic_load(&pos[r], __ATOMIC_RELAXED,
                                          __HIP_MEMORY_SCOPE_AGENT);
        hng = fmaxf(0.0f, p + margin - neg);
    }
    #pragma unroll
    for (int off = 32; off; off >>= 1) hng += __shfl_down(hng, off, 64);
    if (lane == 0) wsum[wave] = hng;
    __syncthreads();
    if (t == 0) {
        float s = 0.0f;
        #pragma unroll
        for (int w = 0; w < 8; ++w) s += wsum[w];
        atomicAdd(out, s * (1.0f / (float)Bt));
    }
}

extern "C" void kernel_launch(void* const* d_in, const int* in_sizes, int n_in,
                              void* d_out, int out_size, void* d_ws, size_t ws_size,
                              hipStream_t stream) {
    const float* x       = (const float*)d_in[0];
    const int*   labels  = (const int*)d_in[1];
    const float* centers = (const float*)d_in[2];
    float* out = (float*)d_out;

    const int Bt = in_sizes[1];           // 65536
    const int D  = in_sizes[0] / Bt;      // 512
    const int C  = in_sizes[2] / D;       // 1000
    const int NT = (C + BN - 1) / BN;     // 8
    const int CP = NT * BN;               // 1024
    const int NB = Bt / BM;               // 256 rowblocks

    char* ws = (char*)d_ws;
    unsigned short* cbf = (unsigned short*)ws;          // CP*D bf16 = 1 MB
    size_t off = (size_t)CP * D * 2;
    off = (off + 255) & ~(size_t)255;
    float* pos = (float*)(ws + off);      off += (size_t)Bt * 4;       // 256 KB
    float* partial = (float*)(ws + off);  off += (size_t)NT * Bt * 4;  // 2 MB
    int* cnt = (int*)(ws + off);          off += (size_t)NB * 4;
    off = (off + 255) & ~(size_t)255;
    unsigned short* xbf = (unsigned short*)(ws + off);   // 64 MB

    const size_t nx = (size_t)Bt * D;
    const int CB = CP / 4;                                // center blocks
    const int XB = (int)((nx / 8 + 255) / 256);           // convert blocks
    prep<<<CB + XB, 256, 0, stream>>>(centers, cbf, C, D, CP, CB, x, xbf, nx,
                                      cnt, NB, out);

    gemm_fused<<<NB * NT, 512, 0, stream>>>(xbf, cbf, labels, pos, partial, cnt,
                                            Bt, C, D, NT, 1.0f, out);
}

// Round 3
// 291.901 us; speedup vs baseline: 1.4233x; 1.4233x over previous
//
#include <hip/hip_runtime.h>
#include <stdint.h>

typedef short v8s __attribute__((ext_vector_type(8)));
typedef short v4s __attribute__((ext_vector_type(4)));
typedef float v4f __attribute__((ext_vector_type(4)));

#define BM 256         // rows per block (8 waves, wave grid 4x2)
#define BN 128
#define BKH 32         // shorts per row per k-step (64 B) -- halved so the
                       // double buffer fits in the same 48 KB as R0
#define TSH ((BM + BN) * BKH)   // shorts per buffer = 12288 (24 KB)
#define POS_INF __builtin_inff()

typedef __attribute__((address_space(3))) unsigned int lds_uint;
typedef const __attribute__((address_space(1))) unsigned int glb_uint;

__device__ __forceinline__ void load16_lds(const void* g, void* l) {
    // 16B per lane, LDS dest = wave-uniform base + lane*16
    __builtin_amdgcn_global_load_lds((glb_uint*)g, (lds_uint*)l, 16, 0, 0);
}

__device__ __forceinline__ short f2bf(float f) {
    uint32_t u = __builtin_bit_cast(uint32_t, f);
    u += 0x7fffu + ((u >> 16) & 1u);
    return (short)(u >> 16);
}

// Fused prep (unchanged from the verified 283us kernel): blocks [0, CB)
// normalize centers (1 row per wave) and pad rows [C, CP) with zeros, plus
// zero the rowblock counters and d_out; blocks [CB, ...) convert x
// fp32->bf16 at pure memory BW.
__global__ void prep(const float* __restrict__ centers,
                     unsigned short* __restrict__ cbf,
                     int C, int D, int CP, int CB,
                     const float* __restrict__ x,
                     unsigned short* __restrict__ xbf, size_t nx,
                     int* __restrict__ cnt, int NB,
                     float* __restrict__ out) {
    const int b = blockIdx.x;
    const int t = threadIdx.x;
    if (b == 0 && t == 0) out[0] = 0.0f;
    if (b < CB) {
        const int g = b * 256 + t;
        if (g < NB) cnt[g] = 0;
        const int wave = t >> 6, lane = t & 63;
        const int row = b * 4 + wave;
        if (row >= CP) return;
        if (row >= C) {
            v4s z = {0, 0, 0, 0};
            for (int d = lane * 4; d < D; d += 256)
                *(v4s*)&cbf[(size_t)row * D + d] = z;
            return;
        }
        const float* src = centers + (size_t)row * D;
        float ss = 0.0f;
        for (int d = lane * 4; d < D; d += 256) {
            v4f f = *(const v4f*)&src[d];
            ss += f.x * f.x + f.y * f.y + f.z * f.z + f.w * f.w;
        }
        #pragma unroll
        for (int off = 32; off; off >>= 1) ss += __shfl_xor(ss, off, 64);
        const float rn = rsqrtf(ss);
        for (int d = lane * 4; d < D; d += 256) {
            v4f f = *(const v4f*)&src[d];
            v4s s;
            s.x = f2bf(f.x * rn); s.y = f2bf(f.y * rn);
            s.z = f2bf(f.z * rn); s.w = f2bf(f.w * rn);
            *(v4s*)&cbf[(size_t)row * D + d] = s;
        }
    } else {
        const size_t i = ((size_t)(b - CB) * 256 + t) * 8;
        if (i >= nx) return;
        v4f f0 = *(const v4f*)&x[i];
        v4f f1 = *(const v4f*)&x[i + 4];
        v8s s;
        s[0] = f2bf(f0.x); s[1] = f2bf(f0.y); s[2] = f2bf(f0.z); s[3] = f2bf(f0.w);
        s[4] = f2bf(f1.x); s[5] = f2bf(f1.y); s[6] = f2bf(f1.z); s[7] = f2bf(f1.w);
        *(v8s*)&xbf[i] = s;
    }
}

// Fused GEMM + row-min epilogue + last-block finisher.
// R3: identical geometry/protocol to the verified 283us kernel (256x128
// tile, 8 waves 4x2, 64x64/wave, 48 KB LDS, 3 blocks/CU, XCD-swizzled
// grid) with ONE structural change: BK 64->32 so the SAME 48 KB holds a
// DOUBLE buffer. k-loop becomes the minimum T3 2-phase pipeline: issue
// next tile's 3 DMA/wave FIRST, then ds_read+MFMA current tile, then one
// __syncthreads per k-step -- the prefetch has the whole compute phase to
// land before the vmcnt(0) drain, removing the cold-stage serialization
// that capped R0 at MfmaUtil 28% (no pipe was >35% busy: pure latency).
//
// Swizzle re-derived for 64 B rows (4 chunks of 16 B): LDS slot chunk c of
// row r holds source chunk c^(r&3); DMA writes base+lane*16 so the SOURCE
// is permuted (rsub=lane>>2, csrc=(lane&3)^(rsub&3)). Reads use slot
// q^(l15&3): each ds_read_b128 is then a bijection onto a contiguous 1 KB
// range -> conflict-free by construction (lane(l15,q) -> unique 16B slot).
// MFMA accumulation stays global-k-ascending -> bit-identical numerics.
//
// Cross-block protocol unchanged: NO acquire/release fences (agent-scope
// ACQ_REL RMW emits buffer_inv/buffer_wbl2 = per-XCD L2 flush; measured
// +59% k-loop time). pos/partial use RELAXED agent-scope atomics;
// __syncthreads drains vmcnt(0) before the RELAXED counter RMW; RMW total
// order + control dependency orders the finisher's relaxed loads.
__global__ void __launch_bounds__(512)
gemm_fused(const unsigned short* __restrict__ xbf,
           const unsigned short* __restrict__ cbf,
           const int* __restrict__ labels,
           float* __restrict__ pos, float* __restrict__ partial,
           int* __restrict__ cnt,
           int Bt, int C, int D, int NT, float margin,
           float* __restrict__ out) {
    __shared__ short LDSbuf[2 * TSH];   // 48 KB total (double-buffered A+B)
    short* As0 = LDSbuf;
    short* Bs0 = LDSbuf + BM * BKH;
    short* As1 = LDSbuf + TSH;
    short* Bs1 = As1 + BM * BKH;

    const int t   = threadIdx.x;
    const int bid = blockIdx.x;
    const int xcd = bid & 7;
    const int per = bid >> 3;
    const int rowblk = (per >> 3) * 8 + xcd;
    const int nt     = per & 7;
    const int row0 = rowblk * BM;
    const int n0   = nt * BN;

    const int lane = t & 63;
    const int wave = t >> 6;          // 0..7
    const int wm = wave >> 1;         // 0..3 -> m offset wm*64
    const int wn = wave & 1;          // 0..1 -> n offset wn*64
    const int l15 = lane & 15, q = lane >> 4;

    // staging lane decomposition: 16 rows x 4 chunks per DMA instruction
    const int rsub = lane >> 2;              // row within 16-row group
    const int csrc = (lane & 3) ^ (rsub & 3);  // swizzled source chunk

    // prefetch this thread's label before the k-loop (latency hidden)
    int myLab = 0;
    if (t < BM) myLab = labels[row0 + t];

    v4f acc[4][4];
    #pragma unroll
    for (int i = 0; i < 4; ++i)
        #pragma unroll
        for (int j = 0; j < 4; ++j)
            acc[i][j] = (v4f){0.f, 0.f, 0.f, 0.f};

    // stage one 24 KB k-step tile (A 16 KB + B 8 KB): 3 DMA instrs/wave
    #define STAGE(As_, Bs_, k0_) do {                                        \
        load16_lds(&xbf[(size_t)(row0 + wave * 32 + rsub) * D + (k0_) + csrc * 8], \
                   &(As_)[(wave * 32) * BKH]);                               \
        load16_lds(&xbf[(size_t)(row0 + wave * 32 + 16 + rsub) * D + (k0_) + csrc * 8], \
                   &(As_)[(wave * 32 + 16) * BKH]);                          \
        load16_lds(&cbf[(size_t)(n0 + wave * 16 + rsub) * D + (k0_) + csrc * 8], \
                   &(Bs_)[(wave * 16) * BKH]);                               \
    } while (0)

    // one k-step: 8 ds_read_b128 + 16 MFMA
    #define TILE(As_, Bs_) do {                                              \
        v8s a[4], b[4];                                                      \
        _Pragma("unroll")                                                    \
        for (int i = 0; i < 4; ++i)                                          \
            a[i] = *(const v8s*)&(As_)[(wm * 64 + i * 16 + l15) * BKH        \
                                       + ((q ^ (l15 & 3)) << 3)];            \
        _Pragma("unroll")                                                    \
        for (int j = 0; j < 4; ++j)                                          \
            b[j] = *(const v8s*)&(Bs_)[(wn * 64 + j * 16 + l15) * BKH        \
                                       + ((q ^ (l15 & 3)) << 3)];            \
        _Pragma("unroll")                                                    \
        for (int i = 0; i < 4; ++i)                                          \
            _Pragma("unroll")                                                \
            for (int j = 0; j < 4; ++j)                                      \
                acc[i][j] = __builtin_amdgcn_mfma_f32_16x16x32_bf16(         \
                    a[i], b[j], acc[i][j], 0, 0, 0);                         \
    } while (0)

    // prologue: tile 0 -> buf0
    STAGE(As0, Bs0, 0);
    __syncthreads();

    const int KT2 = D / (2 * BKH);    // 8 double-steps
    for (int kt2 = 0; kt2 < KT2; ++kt2) {
        const int k0 = kt2 * 64;
        STAGE(As1, Bs1, k0 + 32);                 // prefetch odd tile
        TILE(As0, Bs0);
        __syncthreads();                          // drain: odd tile landed
        if (kt2 + 1 < KT2) STAGE(As0, Bs0, k0 + 64);  // prefetch next even
        TILE(As1, Bs1);
        __syncthreads();                          // drain: even tile landed
    }

    #undef STAGE
    #undef TILE

    // ---- Epilogue (k-loop LDS dead; alias scratch) ----
    int*   Ls    = (int*)LDSbuf;                     // [BM] labels (1 KB)
    float* sMinW = (float*)((char*)LDSbuf + 1024);   // [2*BM] (2 KB)
    int*   sLast = (int*)((char*)LDSbuf + 3072);
    float* wsum  = (float*)((char*)LDSbuf + 3088);   // 8 floats
    if (t < BM) Ls[t] = myLab;
    __syncthreads();

    // dist = 1 - acc; stash pos at label col; row-min over valid cols.
    // C/D layout (16x16x32): col = lane&15, row = q*4 + reg
    #pragma unroll
    for (int i = 0; i < 4; ++i) {
        #pragma unroll
        for (int rg = 0; rg < 4; ++rg) {
            const int row_l = wm * 64 + i * 16 + q * 4 + rg;
            const int lab = Ls[row_l];
            float m = POS_INF;
            #pragma unroll
            for (int j = 0; j < 4; ++j) {
                const int col = n0 + wn * 64 + j * 16 + l15;
                const float d = 1.0f - acc[i][j][rg];
                if (col == lab)
                    __hip_atomic_store(&pos[row0 + row_l], d,
                                       __ATOMIC_RELAXED, __HIP_MEMORY_SCOPE_AGENT);
                else if (col < C) m = fminf(m, d);
            }
            m = fminf(m, __shfl_xor(m, 1, 64));
            m = fminf(m, __shfl_xor(m, 2, 64));
            m = fminf(m, __shfl_xor(m, 4, 64));
            m = fminf(m, __shfl_xor(m, 8, 64));
            if (l15 == 0) sMinW[wn * BM + row_l] = m;
        }
    }
    __syncthreads();
    if (t < BM) {
        const float m = fminf(sMinW[t], sMinW[BM + t]);
        __hip_atomic_store(&partial[(size_t)nt * Bt + row0 + t], m,
                           __ATOMIC_RELAXED, __HIP_MEMORY_SCOPE_AGENT);
    }
    __syncthreads();  // drains vmcnt(0): all stores at coherence point

    // Completion counter: RELAXED on purpose (no buffer_inv/buffer_wbl2).
    if (t == 0) {
        __builtin_amdgcn_s_waitcnt(0);  // belt-and-braces; already drained
        const int old = __hip_atomic_fetch_add(&cnt[rowblk], 1,
                                               __ATOMIC_RELAXED,
                                               __HIP_MEMORY_SCOPE_AGENT);
        *sLast = (old == NT - 1);
    }
    __syncthreads();
    if (!*sLast) return;

    float hng = 0.0f;
    if (t < BM) {
        const int r = row0 + t;
        float neg = POS_INF;
        for (int tt = 0; tt < NT; ++tt)
            neg = fminf(neg, __hip_atomic_load(&partial[(size_t)tt * Bt + r],
                                               __ATOMIC_RELAXED,
                                               __HIP_MEMORY_SCOPE_AGENT));
        const float p = __hip_atomic_load(&pos[r], __ATOMIC_RELAXED,
                                          __HIP_MEMORY_SCOPE_AGENT);
        hng = fmaxf(0.0f, p + margin - neg);
    }
    #pragma unroll
    for (int off = 32; off; off >>= 1) hng += __shfl_down(hng, off, 64);
    if (lane == 0) wsum[wave] = hng;
    __syncthreads();
    if (t == 0) {
        float s = 0.0f;
        #pragma unroll
        for (int w = 0; w < 8; ++w) s += wsum[w];
        atomicAdd(out, s * (1.0f / (float)Bt));
    }
}

extern "C" void kernel_launch(void* const* d_in, const int* in_sizes, int n_in,
                              void* d_out, int out_size, void* d_ws, size_t ws_size,
                              hipStream_t stream) {
    const float* x       = (const float*)d_in[0];
    const int*   labels  = (const int*)d_in[1];
    const float* centers = (const float*)d_in[2];
    float* out = (float*)d_out;

    const int Bt = in_sizes[1];           // 65536
    const int D  = in_sizes[0] / Bt;      // 512
    const int C  = in_sizes[2] / D;       // 1000
    const int NT = (C + BN - 1) / BN;     // 8
    const int CP = NT * BN;               // 1024
    const int NB = Bt / BM;               // 256 rowblocks

    char* ws = (char*)d_ws;
    unsigned short* cbf = (unsigned short*)ws;          // CP*D bf16 = 1 MB
    size_t off = (size_t)CP * D * 2;
    off = (off + 255) & ~(size_t)255;
    float* pos = (float*)(ws + off);      off += (size_t)Bt * 4;       // 256 KB
    float* partial = (float*)(ws + off);  off += (size_t)NT * Bt * 4;  // 2 MB
    int* cnt = (int*)(ws + off);          off += (size_t)NB * 4;
    off = (off + 255) & ~(size_t)255;
    unsigned short* xbf = (unsigned short*)(ws + off);   // 64 MB

    const size_t nx = (size_t)Bt * D;
    const int CB = CP / 4;                                // center blocks
    const int XB = (int)((nx / 8 + 255) / 256);           // convert blocks
    prep<<<CB + XB, 256, 0, stream>>>(centers, cbf, C, D, CP, CB, x, xbf, nx,
                                      cnt, NB, out);

    gemm_fused<<<NB * NT, 512, 0, stream>>>(xbf, cbf, labels, pos, partial, cnt,
                                            Bt, C, D, NT, 1.0f, out);
}

// Round 4
// 285.049 us; speedup vs baseline: 1.4575x; 1.0240x over previous
//
#include <hip/hip_runtime.h>
#include <stdint.h>

typedef short v8s __attribute__((ext_vector_type(8)));
typedef short v4s __attribute__((ext_vector_type(4)));
typedef float v4f __attribute__((ext_vector_type(4)));

#define BM 256         // rows per block (8 waves, wave grid 4x2)
#define BN 128
#define BKH 32         // shorts per row per k-step (64 B)
#define ASH (BM * BKH)          // A region shorts per buffer (16 KB)
#define TSH ((BM + BN) * BKH)   // shorts per buffer = 12288 (24 KB)
#define POS_INF __builtin_inff()

typedef __attribute__((address_space(3))) unsigned int lds_uint;
typedef const __attribute__((address_space(1))) unsigned int glb_uint;

__device__ __forceinline__ void load16_lds(const void* g, void* l) {
    // 16B per lane, LDS dest = wave-uniform base + lane*16
    __builtin_amdgcn_global_load_lds((glb_uint*)g, (lds_uint*)l, 16, 0, 0);
}

__device__ __forceinline__ short f2bf(float f) {
    uint32_t u = __builtin_bit_cast(uint32_t, f);
    u += 0x7fffu + ((u >> 16) & 1u);
    return (short)(u >> 16);
}

// Fused prep (unchanged from the verified 283us kernel).
__global__ void prep(const float* __restrict__ centers,
                     unsigned short* __restrict__ cbf,
                     int C, int D, int CP, int CB,
                     const float* __restrict__ x,
                     unsigned short* __restrict__ xbf, size_t nx,
                     int* __restrict__ cnt, int NB,
                     float* __restrict__ out) {
    const int b = blockIdx.x;
    const int t = threadIdx.x;
    if (b == 0 && t == 0) out[0] = 0.0f;
    if (b < CB) {
        const int g = b * 256 + t;
        if (g < NB) cnt[g] = 0;
        const int wave = t >> 6, lane = t & 63;
        const int row = b * 4 + wave;
        if (row >= CP) return;
        if (row >= C) {
            v4s z = {0, 0, 0, 0};
            for (int d = lane * 4; d < D; d += 256)
                *(v4s*)&cbf[(size_t)row * D + d] = z;
            return;
        }
        const float* src = centers + (size_t)row * D;
        float ss = 0.0f;
        for (int d = lane * 4; d < D; d += 256) {
            v4f f = *(const v4f*)&src[d];
            ss += f.x * f.x + f.y * f.y + f.z * f.z + f.w * f.w;
        }
        #pragma unroll
        for (int off = 32; off; off >>= 1) ss += __shfl_xor(ss, off, 64);
        const float rn = rsqrtf(ss);
        for (int d = lane * 4; d < D; d += 256) {
            v4f f = *(const v4f*)&src[d];
            v4s s;
            s.x = f2bf(f.x * rn); s.y = f2bf(f.y * rn);
            s.z = f2bf(f.z * rn); s.w = f2bf(f.w * rn);
            *(v4s*)&cbf[(size_t)row * D + d] = s;
        }
    } else {
        const size_t i = ((size_t)(b - CB) * 256 + t) * 8;
        if (i >= nx) return;
        v4f f0 = *(const v4f*)&x[i];
        v4f f1 = *(const v4f*)&x[i + 4];
        v8s s;
        s[0] = f2bf(f0.x); s[1] = f2bf(f0.y); s[2] = f2bf(f0.z); s[3] = f2bf(f0.w);
        s[4] = f2bf(f1.x); s[5] = f2bf(f1.y); s[6] = f2bf(f1.z); s[7] = f2bf(f1.w);
        *(v8s*)&xbf[i] = s;
    }
}

// Fused GEMM + row-min epilogue + last-block finisher.
// R4: minimal T3+T4 pipeline on the verified R0 geometry (256x128 tile,
// 8 waves 4x2, 64x64/wave). THREE k-step buffers (BKH=32, 24 KB each,
// 72 KB dynamic LDS -> 2 blocks/CU), ONE raw s_barrier per k-step, and a
// COUNTED s_waitcnt vmcnt(3) per step -- never 0 in the main loop.
// WAITVM(3) = "all but the newest 3 VMEM ops retired"; the newest 3 at
// that point are always the most recent STAGE group, so buf[t] is landed
// while buf[t+1]/buf[t+2] stay in flight: each DMA gets ~2 compute phases
// of latency budget (R0/R3 gave it 0/1 then drained vmcnt(0) -- the m97
// structural stall). Order per step: WAITVM -> s_barrier -> sched_barrier
// -> STAGE(buf[t+2]) -> TILE(buf[t]). Stage-after-barrier makes the WAR
// (overwriting buf[t-1]) barrier-ordered; sched_barrier(0) stops hipcc
// hoisting ds_reads/DMA across the barrier; all ds_read consumers (MFMA)
// are fenced before the next barrier, so reads complete before each wave
// signals. Buffer selection by rotating INTEGER offsets into LDS[] so
// address-space inference keeps ds_read_b128.
//
// Swizzle FIX vs R3 (which was 4-way-conflicted, 8.4M cycles): for 64 B
// rows, slot chunk s of row r holds source chunk s ^ g(r) with
// g(r) = (r>>1)&3 (NOT r&3). Read slot = q ^ g(l15). Bank span =
// 4*(l15&1 ? 4:0) + (q^g): even/odd lanes each spread 2-per-span over 4
// spans -> 16 lanes over 8 spans x 2 (rows differing by 8) = 2-way = free,
// exactly R0's measured-zero profile. DMA source permute:
// csrc = (lane&3) ^ ((lane>>3)&3), rsub = lane>>2.
// MFMA accumulation stays global-k-ascending -> bit-identical numerics.
//
// Cross-block protocol unchanged: NO acquire/release fences (agent-scope
// ACQ_REL RMW emits buffer_inv/buffer_wbl2 = per-XCD L2 flush; measured
// +59% k-loop time). pos/partial use RELAXED agent-scope atomics;
// __syncthreads drains vmcnt(0) before the RELAXED counter RMW; RMW total
// order + control dependency orders the finisher's relaxed loads.
__global__ void __launch_bounds__(512)
gemm_fused(const unsigned short* __restrict__ xbf,
           const unsigned short* __restrict__ cbf,
           const int* __restrict__ labels,
           float* __restrict__ pos, float* __restrict__ partial,
           int* __restrict__ cnt,
           int Bt, int C, int D, int NT, float margin,
           float* __restrict__ out) {
    extern __shared__ short LDS[];   // 3 * TSH shorts = 72 KB

    const int t   = threadIdx.x;
    const int bid = blockIdx.x;
    const int xcd = bid & 7;
    const int per = bid >> 3;
    const int rowblk = (per >> 3) * 8 + xcd;
    const int nt     = per & 7;
    const int row0 = rowblk * BM;
    const int n0   = nt * BN;

    const int lane = t & 63;
    const int wave = t >> 6;          // 0..7
    const int wm = wave >> 1;         // 0..3 -> m offset wm*64
    const int wn = wave & 1;          // 0..1 -> n offset wn*64
    const int l15 = lane & 15, q = lane >> 4;

    // staging lane decomposition: 16 rows x 4 chunks per DMA instruction
    const int rsub = lane >> 2;                     // row within 16-row group
    const int csrc = (lane & 3) ^ ((lane >> 3) & 3);  // g(r) = (r>>1)&3

    // prefetch this thread's label before the k-loop (latency hidden; its
    // vm op is OLDER than every STAGE group, so WAITVM(3) retires it first
    // and the counted-wait arithmetic is unaffected)
    int myLab = 0;
    if (t < BM) myLab = labels[row0 + t];

    v4f acc[4][4];
    #pragma unroll
    for (int i = 0; i < 4; ++i)
        #pragma unroll
        for (int j = 0; j < 4; ++j)
            acc[i][j] = (v4f){0.f, 0.f, 0.f, 0.f};

    // counted waits: "all but newest N VMEM ops retired"
    #define WAITVM3() do { asm volatile("s_waitcnt vmcnt(3)" ::: "memory"); } while (0)
    #define WAITVM0() do { asm volatile("s_waitcnt vmcnt(0)" ::: "memory"); } while (0)
    #define BARRIER() do { __builtin_amdgcn_s_barrier(); \
                           __builtin_amdgcn_sched_barrier(0); } while (0)

    // stage one 24 KB k-step tile (A 16 KB + B 8 KB): 3 DMA instrs/wave
    #define STAGE(buf_, k0_) do {                                            \
        load16_lds(&xbf[(size_t)(row0 + wave * 32 + rsub) * D + (k0_) + csrc * 8], \
                   &LDS[(buf_) + (wave * 32) * BKH]);                        \
        load16_lds(&xbf[(size_t)(row0 + wave * 32 + 16 + rsub) * D + (k0_) + csrc * 8], \
                   &LDS[(buf_) + (wave * 32 + 16) * BKH]);                   \
        load16_lds(&cbf[(size_t)(n0 + wave * 16 + rsub) * D + (k0_) + csrc * 8], \
                   &LDS[(buf_) + ASH + (wave * 16) * BKH]);                  \
    } while (0)

    // one k-step: 8 ds_read_b128 + 16 MFMA; read slot = q ^ ((l15>>1)&3)
    #define TILE(buf_) do {                                                  \
        v8s a[4], b[4];                                                      \
        _Pragma("unroll")                                                    \
        for (int i = 0; i < 4; ++i)                                          \
            a[i] = *(const v8s*)&LDS[(buf_) + (wm * 64 + i * 16 + l15) * BKH \
                                     + ((q ^ ((l15 >> 1) & 3)) << 3)];       \
        _Pragma("unroll")                                                    \
        for (int j = 0; j < 4; ++j)                                          \
            b[j] = *(const v8s*)&LDS[(buf_) + ASH + (wn * 64 + j * 16 + l15) * BKH \
                                     + ((q ^ ((l15 >> 1) & 3)) << 3)];       \
        _Pragma("unroll")                                                    \
        for (int i = 0; i < 4; ++i)                                          \
            _Pragma("unroll")                                                \
            for (int j = 0; j < 4; ++j)                                      \
                acc[i][j] = __builtin_amdgcn_mfma_f32_16x16x32_bf16(         \
                    a[i], b[j], acc[i][j], 0, 0, 0);                         \
    } while (0)

    // rotating buffer base offsets (ints, not pointers: keeps AS3 inference)
    int bc = 0, b1 = TSH, b2 = 2 * TSH;

    // prologue: fill the pipeline 2 deep
    STAGE(bc, 0);
    STAGE(b1, BKH);

    const int KT = D / BKH;          // 16
    for (int kt = 0; kt + 2 < KT; ++kt) {
        WAITVM3();                   // buf[kt] landed; kt+1 stays in flight
        BARRIER();                   // all waves' buf[kt] visible; WAR safe
        STAGE(b2, (kt + 2) * BKH);   // refill depth (overwrites buf[kt-1])
        TILE(bc);
        const int tmp = bc; bc = b1; b1 = b2; b2 = tmp;
    }
    // kt = KT-2: no stage left to issue
    WAITVM3();
    BARRIER();
    TILE(bc);
    // kt = KT-1: final buffer -> full drain is exact here
    WAITVM0();
    BARRIER();
    TILE(b1);

    #undef STAGE
    #undef TILE
    #undef WAITVM3
    #undef WAITVM0
    #undef BARRIER

    __syncthreads();   // all reads done before LDS reuse; drains counters

    // ---- Epilogue (k-loop LDS dead; alias scratch) ----
    int*   Ls    = (int*)LDS;                     // [BM] labels (1 KB)
    float* sMinW = (float*)((char*)LDS + 1024);   // [2*BM] (2 KB)
    int*   sLast = (int*)((char*)LDS + 3072);
    float* wsum  = (float*)((char*)LDS + 3088);   // 8 floats
    if (t < BM) Ls[t] = myLab;
    __syncthreads();

    // dist = 1 - acc; stash pos at label col; row-min over valid cols.
    // C/D layout (16x16x32): col = lane&15, row = q*4 + reg
    #pragma unroll
    for (int i = 0; i < 4; ++i) {
        #pragma unroll
        for (int rg = 0; rg < 4; ++rg) {
            const int row_l = wm * 64 + i * 16 + q * 4 + rg;
            const int lab = Ls[row_l];
            float m = POS_INF;
            #pragma unroll
            for (int j = 0; j < 4; ++j) {
                const int col = n0 + wn * 64 + j * 16 + l15;
                const float d = 1.0f - acc[i][j][rg];
                if (col == lab)
                    __hip_atomic_store(&pos[row0 + row_l], d,
                                       __ATOMIC_RELAXED, __HIP_MEMORY_SCOPE_AGENT);
                else if (col < C) m = fminf(m, d);
            }
            m = fminf(m, __shfl_xor(m, 1, 64));
            m = fminf(m, __shfl_xor(m, 2, 64));
            m = fminf(m, __shfl_xor(m, 4, 64));
            m = fminf(m, __shfl_xor(m, 8, 64));
            if (l15 == 0) sMinW[wn * BM + row_l] = m;
        }
    }
    __syncthreads();
    if (t < BM) {
        const float m = fminf(sMinW[t], sMinW[BM + t]);
        __hip_atomic_store(&partial[(size_t)nt * Bt + row0 + t], m,
                           __ATOMIC_RELAXED, __HIP_MEMORY_SCOPE_AGENT);
    }
    __syncthreads();  // drains vmcnt(0): all stores at coherence point

    // Completion counter: RELAXED on purpose (no buffer_inv/buffer_wbl2).
    if (t == 0) {
        __builtin_amdgcn_s_waitcnt(0);  // belt-and-braces; already drained
        const int old = __hip_atomic_fetch_add(&cnt[rowblk], 1,
                                               __ATOMIC_RELAXED,
                                               __HIP_MEMORY_SCOPE_AGENT);
        *sLast = (old == NT - 1);
    }
    __syncthreads();
    if (!*sLast) return;

    float hng = 0.0f;
    if (t < BM) {
        const int r = row0 + t;
        float neg = POS_INF;
        for (int tt = 0; tt < NT; ++tt)
            neg = fminf(neg, __hip_atomic_load(&partial[(size_t)tt * Bt + r],
                                               __ATOMIC_RELAXED,
                                               __HIP_MEMORY_SCOPE_AGENT));
        const float p = __hip_atomic_load(&pos[r], __ATOMIC_RELAXED,
                                          __HIP_MEMORY_SCOPE_AGENT);
        hng = fmaxf(0.0f, p + margin - neg);
    }
    #pragma unroll
    for (int off = 32; off; off >>= 1) hng += __shfl_down(hng, off, 64);
    if (lane == 0) wsum[wave] = hng;
    __syncthreads();
    if (t == 0) {
        float s = 0.0f;
        #pragma unroll
        for (int w = 0; w < 8; ++w) s += wsum[w];
        atomicAdd(out, s * (1.0f / (float)Bt));
    }
}

extern "C" void kernel_launch(void* const* d_in, const int* in_sizes, int n_in,
                              void* d_out, int out_size, void* d_ws, size_t ws_size,
                              hipStream_t stream) {
    const float* x       = (const float*)d_in[0];
    const int*   labels  = (const int*)d_in[1];
    const float* centers = (const float*)d_in[2];
    float* out = (float*)d_out;

    const int Bt = in_sizes[1];           // 65536
    const int D  = in_sizes[0] / Bt;      // 512
    const int C  = in_sizes[2] / D;       // 1000
    const int NT = (C + BN - 1) / BN;     // 8
    const int CP = NT * BN;               // 1024
    const int NB = Bt / BM;               // 256 rowblocks

    char* ws = (char*)d_ws;
    unsigned short* cbf = (unsigned short*)ws;          // CP*D bf16 = 1 MB
    size_t off = (size_t)CP * D * 2;
    off = (off + 255) & ~(size_t)255;
    float* pos = (float*)(ws + off);      off += (size_t)Bt * 4;       // 256 KB
    float* partial = (float*)(ws + off);  off += (size_t)NT * Bt * 4;  // 2 MB
    int* cnt = (int*)(ws + off);          off += (size_t)NB * 4;
    off = (off + 255) & ~(size_t)255;
    unsigned short* xbf = (unsigned short*)(ws + off);   // 64 MB

    const size_t nx = (size_t)Bt * D;
    const int CB = CP / 4;                                // center blocks
    const int XB = (int)((nx / 8 + 255) / 256);           // convert blocks
    prep<<<CB + XB, 256, 0, stream>>>(centers, cbf, C, D, CP, CB, x, xbf, nx,
                                      cnt, NB, out);

    // 72 KB dynamic LDS needs the opt-in attribute (one-time, host-side,
    // not a stream op -> graph-capture safe).
    static bool lds_attr_set = false;
    if (!lds_attr_set) {
        hipFuncSetAttribute(reinterpret_cast<const void*>(gemm_fused),
                            hipFuncAttributeMaxDynamicSharedMemorySize,
                            3 * TSH * (int)sizeof(short));
        lds_attr_set = true;
    }
    gemm_fused<<<NB * NT, 512, 3 * TSH * sizeof(short), stream>>>(
        xbf, cbf, labels, pos, partial, cnt, Bt, C, D, NT, 1.0f, out);
}